// Round 9
// baseline (178.585 us; speedup 1.0000x reference)
//
#include <hip/hip_runtime.h>

// Problem constants
#define B_  2
#define S_  1024
#define FIN 768
#define E_  768
#define H_  12
#define DH  64   // = FH = 64

typedef unsigned int uint;
typedef unsigned short ushort;
typedef __attribute__((ext_vector_type(8))) short short8;    // 8 bf16 (4 VGPRs)
typedef __attribute__((ext_vector_type(4))) float floatx4;   // MFMA acc

__device__ __forceinline__ ushort f2bf(float f) {   // RNE float->bf16 bits
    uint u = __float_as_uint(f);
    return (ushort)((u + 0x7fffu + ((u >> 16) & 1u)) >> 16);
}

__device__ __forceinline__ uint4 pack8(const ushort* p) {
    uint4 r;
    r.x = (uint)p[0] | ((uint)p[1] << 16);
    r.y = (uint)p[2] | ((uint)p[3] << 16);
    r.z = (uint)p[4] | ((uint)p[5] << 16);
    r.w = (uint)p[6] | ((uint)p[7] << 16);
    return r;
}

__device__ __forceinline__ void split8v(float4 a, float4 b, short8& hi, short8& lo) {
    float v[8] = {a.x, a.y, a.z, a.w, b.x, b.y, b.z, b.w};
    ushort h[8], l[8];
#pragma unroll
    for (int j = 0; j < 8; ++j) {
        h[j] = f2bf(v[j]);
        l[j] = f2bf(v[j] - __uint_as_float(((uint)h[j]) << 16));
    }
    uint4 H = pack8(h), L = pack8(l);
    hi = *(short8*)&H;
    lo = *(short8*)&L;
}

// ---------------------------------------------------------------------------
// K1: combined prep.
//  block 0:        Wn/WnT (row-normalized nnmf_w) + r1inv.
//  blocks 1..26:   zero mp0 (24576) + M (1536) (contiguous 26112 floats).
//  blocks 27..1082: convert x and ew to split-bf16 planes (Xh/Xl, Eh/El).
// ---------------------------------------------------------------------------
__global__ __launch_bounds__(256) void k_prep(const float* __restrict__ nw,
                                              const float* __restrict__ xs,
                                              const float* __restrict__ ew,
                                              float* __restrict__ Wn,
                                              float* __restrict__ WnT,
                                              float* __restrict__ r1inv,
                                              float* __restrict__ zbase,
                                              ushort* __restrict__ Xh,
                                              ushort* __restrict__ Xl,
                                              ushort* __restrict__ Eh,
                                              ushort* __restrict__ El) {
    const int tid = threadIdx.x;
    if (blockIdx.x == 0) {
        __shared__ float Wl[64 * 65];
        const int f = tid >> 2, q = tid & 3;
        float v[16];
        float s = 0.f;
#pragma unroll
        for (int i = 0; i < 16; ++i) { v[i] = nw[f * 64 + q * 16 + i]; s += v[i]; }
        s += __shfl_xor(s, 1, 64);
        s += __shfl_xor(s, 2, 64);
        const float inv = 1.f / fmaxf(s, 1e-20f);
#pragma unroll
        for (int i = 0; i < 16; ++i) {
            float w = v[i] * inv;
            Wn[f * 64 + q * 16 + i] = w;
            WnT[(q * 16 + i) * 64 + f] = w;
            Wl[f * 65 + q * 16 + i] = w;
        }
        __syncthreads();
        if (tid < 64) {
            float cs = 0.f;
            for (int ff = 0; ff < 64; ++ff) cs += Wl[ff * 65 + tid];
            float t = fmaxf(cs * (1.f / 64.f), 1e-6f);
            float S = t;
#pragma unroll
            for (int m = 1; m < 64; m <<= 1) S += __shfl_xor(S, m, 64);
            S = fmaxf(S, 1e-20f);
            r1inv[tid] = S / t;   // 1/rec1
        }
    } else if (blockIdx.x <= 26) {
        const int i = (blockIdx.x - 1) * 1024 + tid * 4;
        if (i < 26112) {
            float4 z = make_float4(0.f, 0.f, 0.f, 0.f);
            *(float4*)(zbase + i) = z;
        }
    } else {
        int ci = (blockIdx.x - 27) * 256 + tid;   // 0..270335
        const float* src;
        ushort* dh;
        ushort* dl;
        if (ci < 196608) { src = xs; dh = Xh; dl = Xl; }
        else { ci -= 196608; src = ew; dh = Eh; dl = El; }
        const size_t off = (size_t)ci * 8;
        float4 a = *(const float4*)(src + off);
        float4 b = *(const float4*)(src + off + 4);
        float v[8] = {a.x, a.y, a.z, a.w, b.x, b.y, b.z, b.w};
        ushort h[8], l[8];
#pragma unroll
        for (int j = 0; j < 8; ++j) {
            h[j] = f2bf(v[j]);
            l[j] = f2bf(v[j] - __uint_as_float(((uint)h[j]) << 16));
        }
        *(uint4*)(dh + off) = pack8(h);
        *(uint4*)(dl + off) = pack8(l);
    }
}

// ---------------------------------------------------------------------------
// K2 v6 (MFMA, pre-converted planes): xe = clip(x @ embed_w^T + b, 1e-6);
// inp = l1norm per head. Hot loop is pure ds_read_b128 + MFMA — no f2bf.
// ---------------------------------------------------------------------------
__global__ __launch_bounds__(256) void k_embed(const ushort* __restrict__ Xh,
                                               const ushort* __restrict__ Xl,
                                               const ushort* __restrict__ Eh,
                                               const ushort* __restrict__ El,
                                               const float* __restrict__ eb,
                                               float* __restrict__ inp) {
    __shared__ ushort As_hi[64 * 72], As_lo[64 * 72];
    __shared__ ushort Bs_hi[64 * 72], Bs_lo[64 * 72];
    __shared__ float RS[2][64];
    const int tid = threadIdx.x;
    const int head = blockIdx.y;
    const int tok0 = blockIdx.x * 64;
    const int wv = tid >> 6, lane = tid & 63;
    const int mbase = (wv >> 1) * 32, nbase = (wv & 1) * 32;
    const int lm = lane & 15, lq = lane >> 4;

    floatx4 acc[2][2];
#pragma unroll
    for (int si = 0; si < 2; ++si)
#pragma unroll
        for (int ti = 0; ti < 2; ++ti) acc[si][ti] = (floatx4)0.f;

    const int row = tid >> 2;            // 0..63 (tok for A, out for B)
    const int kq = (tid & 3) * 16;       // 16 k per thread per panel
    const ushort* xh = Xh + (size_t)(tok0 + row) * FIN + kq;
    const ushort* xl = Xl + (size_t)(tok0 + row) * FIN + kq;
    const ushort* ehp = Eh + (size_t)(head * 64 + row) * FIN + kq;
    const ushort* elp = El + (size_t)(head * 64 + row) * FIN + kq;

    uint4 pah[2], pal[2], pbh[2], pbl[2];
#pragma unroll
    for (int c = 0; c < 2; ++c) {
        pah[c] = *(const uint4*)(xh + c * 8);
        pal[c] = *(const uint4*)(xl + c * 8);
        pbh[c] = *(const uint4*)(ehp + c * 8);
        pbl[c] = *(const uint4*)(elp + c * 8);
    }

    for (int kb = 0; kb < FIN; kb += 64) {
        __syncthreads();   // previous panel's frag reads done
        {
            const int off = row * 72 + kq;
            *(uint4*)&As_hi[off]     = pah[0];
            *(uint4*)&As_hi[off + 8] = pah[1];
            *(uint4*)&As_lo[off]     = pal[0];
            *(uint4*)&As_lo[off + 8] = pal[1];
            *(uint4*)&Bs_hi[off]     = pbh[0];
            *(uint4*)&Bs_hi[off + 8] = pbh[1];
            *(uint4*)&Bs_lo[off]     = pbl[0];
            *(uint4*)&Bs_lo[off + 8] = pbl[1];
        }
        __syncthreads();
        if (kb + 64 < FIN) {   // prefetch next panel during compute
#pragma unroll
            for (int c = 0; c < 2; ++c) {
                pah[c] = *(const uint4*)(xh + kb + 64 + c * 8);
                pal[c] = *(const uint4*)(xl + kb + 64 + c * 8);
                pbh[c] = *(const uint4*)(ehp + kb + 64 + c * 8);
                pbl[c] = *(const uint4*)(elp + kb + 64 + c * 8);
            }
        }
#pragma unroll
        for (int ch = 0; ch < 2; ++ch) {
            const int ko = ch * 32 + lq * 8;
            short8 ah[2], al[2], bh[2], bl[2];
#pragma unroll
            for (int si = 0; si < 2; ++si) {
                ah[si] = *(const short8*)&As_hi[(mbase + si * 16 + lm) * 72 + ko];
                al[si] = *(const short8*)&As_lo[(mbase + si * 16 + lm) * 72 + ko];
            }
#pragma unroll
            for (int ti = 0; ti < 2; ++ti) {
                bh[ti] = *(const short8*)&Bs_hi[(nbase + ti * 16 + lm) * 72 + ko];
                bl[ti] = *(const short8*)&Bs_lo[(nbase + ti * 16 + lm) * 72 + ko];
            }
#pragma unroll
            for (int si = 0; si < 2; ++si)
#pragma unroll
                for (int ti = 0; ti < 2; ++ti) {
                    acc[si][ti] = __builtin_amdgcn_mfma_f32_16x16x32_bf16(
                        ah[si], bh[ti], acc[si][ti], 0, 0, 0);
                    acc[si][ti] = __builtin_amdgcn_mfma_f32_16x16x32_bf16(
                        al[si], bh[ti], acc[si][ti], 0, 0, 0);
                    acc[si][ti] = __builtin_amdgcn_mfma_f32_16x16x32_bf16(
                        ah[si], bl[ti], acc[si][ti], 0, 0, 0);
                }
        }
    }

    // epilogue: bias, clamp, per-token l1norm over 64 outs, store.
    const int half = wv & 1;
    const float b0 = eb[head * 64 + nbase + lm];
    const float b1 = eb[head * 64 + nbase + 16 + lm];
    float xe[2][2][4];
#pragma unroll
    for (int si = 0; si < 2; ++si) {
        float rs[4];
#pragma unroll
        for (int r = 0; r < 4; ++r) {
            float e0 = fmaxf(acc[si][0][r] + b0, 1e-6f);
            float e1 = fmaxf(acc[si][1][r] + b1, 1e-6f);
            xe[si][0][r] = e0; xe[si][1][r] = e1;
            rs[r] = e0 + e1;
        }
#pragma unroll
        for (int r = 0; r < 4; ++r) {
            rs[r] += __shfl_xor(rs[r], 1, 64);
            rs[r] += __shfl_xor(rs[r], 2, 64);
            rs[r] += __shfl_xor(rs[r], 4, 64);
            rs[r] += __shfl_xor(rs[r], 8, 64);
        }
        if (lm == 0) {
#pragma unroll
            for (int r = 0; r < 4; ++r)
                RS[half][mbase + si * 16 + lq * 4 + r] = rs[r];
        }
    }
    __syncthreads();
    const size_t obase = ((size_t)((tok0 >> 10) * 12 + head) * 1024 + (tok0 & 1023));
#pragma unroll
    for (int si = 0; si < 2; ++si)
#pragma unroll
        for (int r = 0; r < 4; ++r) {
            const int m = mbase + si * 16 + lq * 4 + r;
            const float inv = 1.f / fmaxf(RS[0][m] + RS[1][m], 1e-20f);
            float* op = inp + (obase + m) * 64;
            op[nbase + lm]      = xe[si][0][r] * inv;
            op[nbase + 16 + lm] = xe[si][1][r] * inv;
        }
}

// ---------------------------------------------------------------------------
// K3 (MFMA, passed R8): NNMF updates, 16 tokens per wave, 384 blocks x 4 waves.
// ---------------------------------------------------------------------------
__device__ __forceinline__ void mfma_matvec(const float srcC[4][4], float* T,
                                            int lm, int lq,
                                            const short8 Bh[4][2],
                                            const short8 Bl[4][2],
                                            floatx4 out[4]) {
#pragma unroll
    for (int nt = 0; nt < 4; ++nt)
#pragma unroll
        for (int r = 0; r < 4; ++r)
            T[(lq * 4 + r) * 68 + nt * 16 + lm] = srcC[nt][r];
    __syncthreads();
    float4 a00 = *(const float4*)&T[lm * 68 + lq * 8];
    float4 a01 = *(const float4*)&T[lm * 68 + lq * 8 + 4];
    float4 a10 = *(const float4*)&T[lm * 68 + 32 + lq * 8];
    float4 a11 = *(const float4*)&T[lm * 68 + 32 + lq * 8 + 4];
    short8 A0h, A0l, A1h, A1l;
    split8v(a00, a01, A0h, A0l);
    split8v(a10, a11, A1h, A1l);
#pragma unroll
    for (int nt = 0; nt < 4; ++nt) {
        floatx4 acc = (floatx4)0.f;
        acc = __builtin_amdgcn_mfma_f32_16x16x32_bf16(A0h, Bh[nt][0], acc, 0, 0, 0);
        acc = __builtin_amdgcn_mfma_f32_16x16x32_bf16(A0l, Bh[nt][0], acc, 0, 0, 0);
        acc = __builtin_amdgcn_mfma_f32_16x16x32_bf16(A0h, Bl[nt][0], acc, 0, 0, 0);
        acc = __builtin_amdgcn_mfma_f32_16x16x32_bf16(A1h, Bh[nt][1], acc, 0, 0, 0);
        acc = __builtin_amdgcn_mfma_f32_16x16x32_bf16(A1l, Bh[nt][1], acc, 0, 0, 0);
        acc = __builtin_amdgcn_mfma_f32_16x16x32_bf16(A1h, Bl[nt][1], acc, 0, 0, 0);
        out[nt] = acc;
    }
}

__global__ __launch_bounds__(256) void k_nnmf(const float* __restrict__ inp,
                                              const float* __restrict__ Wn,
                                              const float* __restrict__ WnT,
                                              const float* __restrict__ r1inv,
                                              float* __restrict__ hout,
                                              float* __restrict__ hriout,
                                              float* __restrict__ mp0) {
    __shared__ float Tb[4][16 * 68];
    const int tid = threadIdx.x, wv = tid >> 6, lane = tid & 63;
    const int lm = lane & 15, lq = lane >> 4;
    float* T = Tb[wv];
    const int rowbase = blockIdx.x * 64 + wv * 16;

    short8 Bt_h[4][2], Bt_l[4][2], Bw_h[4][2], Bw_l[4][2];
#pragma unroll
    for (int nt = 0; nt < 4; ++nt)
#pragma unroll
        for (int kc = 0; kc < 2; ++kc) {
            const int idx = (nt * 16 + lm) * 64 + kc * 32 + lq * 8;
            split8v(*(const float4*)(WnT + idx), *(const float4*)(WnT + idx + 4),
                    Bt_h[nt][kc], Bt_l[nt][kc]);
            split8v(*(const float4*)(Wn + idx), *(const float4*)(Wn + idx + 4),
                    Bw_h[nt][kc], Bw_l[nt][kc]);
        }

    float inpC[4][4];
#pragma unroll
    for (int nt = 0; nt < 4; ++nt)
#pragma unroll
        for (int r = 0; r < 4; ++r)
            inpC[nt][r] = inp[(size_t)(rowbase + lq * 4 + r) * 64 + nt * 16 + lm];
    float r1c[4];
#pragma unroll
    for (int nt = 0; nt < 4; ++nt) r1c[nt] = r1inv[nt * 16 + lm];

    float hC[4][4], recC[4][4];
    {   // ---- iteration 1 (rec1 token-independent) ----
        float qC[4][4];
#pragma unroll
        for (int nt = 0; nt < 4; ++nt)
#pragma unroll
            for (int r = 0; r < 4; ++r) qC[nt][r] = inpC[nt][r] * r1c[nt];
        floatx4 u[4];
        mfma_matvec(qC, T, lm, lq, Bw_h, Bw_l, u);
#pragma unroll
        for (int nt = 0; nt < 4; ++nt)
#pragma unroll
            for (int r = 0; r < 4; ++r)
                hC[nt][r] = fmaxf(u[nt][r] * (1.f / 64.f), 1e-6f);
#pragma unroll
        for (int r = 0; r < 4; ++r) {
            float s = (hC[0][r] + hC[1][r]) + (hC[2][r] + hC[3][r]);
            s += __shfl_xor(s, 1, 64); s += __shfl_xor(s, 2, 64);
            s += __shfl_xor(s, 4, 64); s += __shfl_xor(s, 8, 64);
            const float inv = __builtin_amdgcn_rcpf(fmaxf(s, 1e-20f));
#pragma unroll
            for (int nt = 0; nt < 4; ++nt) hC[nt][r] *= inv;
        }
    }
#pragma unroll 1
    for (int it = 0; it < 2; ++it) {   // ---- iterations 2,3 (full) ----
        floatx4 t[4];
        mfma_matvec(hC, T, lm, lq, Bt_h, Bt_l, t);
        float tC[4][4], qC[4][4];
#pragma unroll
        for (int nt = 0; nt < 4; ++nt)
#pragma unroll
            for (int r = 0; r < 4; ++r) tC[nt][r] = fmaxf(t[nt][r], 1e-6f);
#pragma unroll
        for (int r = 0; r < 4; ++r) {
            float s = (tC[0][r] + tC[1][r]) + (tC[2][r] + tC[3][r]);
            s += __shfl_xor(s, 1, 64); s += __shfl_xor(s, 2, 64);
            s += __shfl_xor(s, 4, 64); s += __shfl_xor(s, 8, 64);
            s = fmaxf(s, 1e-20f);
            const float invS = __builtin_amdgcn_rcpf(s);
#pragma unroll
            for (int nt = 0; nt < 4; ++nt) {
                recC[nt][r] = tC[nt][r] * invS;
                qC[nt][r] = inpC[nt][r] * s * __builtin_amdgcn_rcpf(tC[nt][r]);
            }
        }
        floatx4 u[4];
        mfma_matvec(qC, T, lm, lq, Bw_h, Bw_l, u);
#pragma unroll
        for (int nt = 0; nt < 4; ++nt)
#pragma unroll
            for (int r = 0; r < 4; ++r)
                hC[nt][r] = fmaxf(hC[nt][r] * u[nt][r], 1e-6f);
#pragma unroll
        for (int r = 0; r < 4; ++r) {
            float s = (hC[0][r] + hC[1][r]) + (hC[2][r] + hC[3][r]);
            s += __shfl_xor(s, 1, 64); s += __shfl_xor(s, 2, 64);
            s += __shfl_xor(s, 4, 64); s += __shfl_xor(s, 8, 64);
            const float inv = __builtin_amdgcn_rcpf(fmaxf(s, 1e-20f));
#pragma unroll
            for (int nt = 0; nt < 4; ++nt) hC[nt][r] *= inv;
        }
    }
#pragma unroll
    for (int r = 0; r < 4; ++r) {
        float s = (hC[0][r] + hC[1][r]) + (hC[2][r] + hC[3][r]);
        s += __shfl_xor(s, 1, 64); s += __shfl_xor(s, 2, 64);
        s += __shfl_xor(s, 4, 64); s += __shfl_xor(s, 8, 64);
        const float inv = __builtin_amdgcn_rcpf(fmaxf(s, 1e-20f));
#pragma unroll
        for (int nt = 0; nt < 4; ++nt) hC[nt][r] *= inv;
    }
#pragma unroll
    for (int nt = 0; nt < 4; ++nt)
#pragma unroll
        for (int r = 0; r < 4; ++r) {
            const size_t o = (size_t)(rowbase + lq * 4 + r) * 64 + nt * 16 + lm;
            hout[o] = hC[nt][r];
            hriout[o] = recC[nt][r] * inpC[nt][r];
        }
    float hs[4];
#pragma unroll
    for (int nt = 0; nt < 4; ++nt) {
        float s = (hC[nt][0] + hC[nt][1]) + (hC[nt][2] + hC[nt][3]);
        s += __shfl_xor(s, 16, 64);
        s += __shfl_xor(s, 32, 64);
        hs[nt] = s;
    }
    float mvv = lq == 0 ? hs[0] : lq == 1 ? hs[1] : lq == 2 ? hs[2] : hs[3];
    atomicAdd(&mp0[(size_t)blockIdx.x * 64 + lq * 16 + lm], mvv);
}

// ---------------------------------------------------------------------------
// K4: one alpha iteration per launch, 384 blocks = (bh) x (64-o chunk).
// ---------------------------------------------------------------------------
__global__ __launch_bounds__(256) void k_alpha_step(const float* __restrict__ hin,
                                                    const float* __restrict__ hri,
                                                    const float* __restrict__ Wn,
                                                    const float* __restrict__ mp_in,
                                                    float* __restrict__ mp_out,
                                                    float* __restrict__ c,
                                                    float* __restrict__ M,
                                                    int it) {
    __shared__ float mred[4][64];
    __shared__ float mv[64];
    __shared__ float vv[64];
    __shared__ float cl[64];
    const int tid = threadIdx.x;
    const int bh = blockIdx.x >> 4;
    const int chunk = blockIdx.x & 15;
    const size_t rowbase = (size_t)bh * 1024 + chunk * 64;

    {
        int f = tid & 63, p = tid >> 6;
        float s = 0.f;
#pragma unroll
        for (int pp = 0; pp < 4; ++pp)
            s += mp_in[((size_t)bh * 16 + p * 4 + pp) * 64 + f];
        mred[p][f] = s;
    }
    __syncthreads();
    if (tid < 64)
        mv[tid] = (mred[0][tid] + mred[1][tid]) + (mred[2][tid] + mred[3][tid]);
    __syncthreads();
    {
        int d = tid & 63, qq = tid >> 6;
        float r = 0.f;
#pragma unroll
        for (int ff = 0; ff < 16; ++ff)
            r = fmaf(mv[qq * 16 + ff], Wn[(size_t)(qq * 16 + ff) * 64 + d], r);
        mred[qq][d] = r;
    }
    __syncthreads();
    if (tid < 64)
        vv[tid] = 1.f / (((mred[0][tid] + mred[1][tid]) + (mred[2][tid] + mred[3][tid])) + 1e-20f);
    __syncthreads();
    {
        int o = tid >> 2, dq = tid & 3;
        const float* rp = hri + (rowbase + o) * 64 + dq * 16;
        float dot = 0.f;
#pragma unroll
        for (int t4 = 0; t4 < 16; t4 += 4) {
            float4 r4 = *(const float4*)(rp + t4);
            dot = fmaf(r4.x, vv[dq * 16 + t4 + 0], dot);
            dot = fmaf(r4.y, vv[dq * 16 + t4 + 1], dot);
            dot = fmaf(r4.z, vv[dq * 16 + t4 + 2], dot);
            dot = fmaf(r4.w, vv[dq * 16 + t4 + 3], dot);
        }
        dot += __shfl_xor(dot, 1, 64);
        dot += __shfl_xor(dot, 2, 64);
        float cn = dot;
        if (it >= 2) cn *= c[rowbase + o];
        if (dq == 0) { c[rowbase + o] = cn; cl[o] = cn; }
    }
    __syncthreads();
    {
        const int f4 = (tid & 15) * 4, ogr = tid >> 4;
        float4 a = make_float4(0.f, 0.f, 0.f, 0.f);
#pragma unroll
        for (int oi = 0; oi < 4; ++oi) {
            int o = ogr * 4 + oi;
            float4 h4 = *(const float4*)(hin + (rowbase + o) * 64 + f4);
            float cv = cl[o];
            a.x = fmaf(h4.x, cv, a.x); a.y = fmaf(h4.y, cv, a.y);
            a.z = fmaf(h4.z, cv, a.z); a.w = fmaf(h4.w, cv, a.w);
        }
        a.x += __shfl_xor(a.x, 16, 64); a.y += __shfl_xor(a.y, 16, 64);
        a.z += __shfl_xor(a.z, 16, 64); a.w += __shfl_xor(a.w, 16, 64);
        a.x += __shfl_xor(a.x, 32, 64); a.y += __shfl_xor(a.y, 32, 64);
        a.z += __shfl_xor(a.z, 32, 64); a.w += __shfl_xor(a.w, 32, 64);
        const int w = tid >> 6;
        if ((tid & 63) < 16) *(float4*)&mred[w][(tid & 15) * 4] = a;
    }
    __syncthreads();
    if (tid < 64) {
        float s = (mred[0][tid] + mred[1][tid]) + (mred[2][tid] + mred[3][tid]);
        if (it == 3) atomicAdd(&M[(size_t)bh * 64 + tid], s);
        else mp_out[((size_t)bh * 16 + chunk) * 64 + tid] = s;
    }
}

// ---------------------------------------------------------------------------
// K5: out-projection + broadcast, 384 blocks = (b) x (12 out-seg) x (16 rowgrp).
// ---------------------------------------------------------------------------
__global__ __launch_bounds__(256) void k_projbcast(const float* __restrict__ M,
                                                   const float* __restrict__ ow,
                                                   const float* __restrict__ ob,
                                                   float* __restrict__ out) {
    __shared__ float Ml[768];
    __shared__ float ps[4][64];
    __shared__ float yseg[64];
    const int tid = threadIdx.x;
    const int b = blockIdx.x / 192;
    const int rem = blockIdx.x - b * 192;
    const int jt = rem >> 4, rg = rem & 15;
    for (int i = tid; i < 768; i += 256) Ml[i] = M[b * 768 + i];
    __syncthreads();
    const int jj = tid & 63, part = tid >> 6;
    const int j = jt * 64 + jj;
    const float* row = ow + (size_t)j * 768 + part * 192;
    float acc = 0.f;
    for (int t = 0; t < 192; t += 4) {
        float4 w4 = *(const float4*)(row + t);
        acc = fmaf(w4.x, Ml[part * 192 + t + 0], acc);
        acc = fmaf(w4.y, Ml[part * 192 + t + 1], acc);
        acc = fmaf(w4.z, Ml[part * 192 + t + 2], acc);
        acc = fmaf(w4.w, Ml[part * 192 + t + 3], acc);
    }
    ps[part][jj] = acc;
    __syncthreads();
    if (tid < 64)
        yseg[tid] = ps[0][tid] + ps[1][tid] + ps[2][tid] + ps[3][tid] + ob[jt * 64 + tid];
    __syncthreads();
    const int r0 = tid >> 2, c4 = (tid & 3) * 16;
    float4 v4[4];
#pragma unroll
    for (int q = 0; q < 4; ++q) v4[q] = *(const float4*)&yseg[c4 + q * 4];
    float* dst = out + ((size_t)(b * 1024 + rg * 64 + r0)) * 768 + jt * 64 + c4;
#pragma unroll
    for (int q = 0; q < 4; ++q) *(float4*)(dst + q * 4) = v4[q];
}

extern "C" void kernel_launch(void* const* d_in, const int* in_sizes, int n_in,
                              void* d_out, int out_size, void* d_ws, size_t ws_size,
                              hipStream_t stream) {
    const float* xs = (const float*)d_in[0];  // [2,1024,768]
    const float* ew = (const float*)d_in[1];  // [768,768]
    const float* eb = (const float*)d_in[2];  // [768]
    const float* nw = (const float*)d_in[3];  // [64,64]
    const float* ow = (const float*)d_in[4];  // [768,768]
    const float* ob = (const float*)d_in[5];  // [768]
    float* out = (float*)d_out;               // [2,1024,768]

    float* ws    = (float*)d_ws;
    float* inp   = ws;                 // 1572864
    float* h     = ws + 1572864;       // 1572864
    float* hri   = ws + 3145728;       // 1572864
    float* Wn    = ws + 4718592;       // 4096
    float* WnT   = ws + 4722688;       // 4096
    float* r1inv = ws + 4726784;       // 256
    float* mp0   = ws + 4727040;       // 24576 (atomic target, zeroed by k_prep)
    float* M     = ws + 4751616;       // 1536  (atomic target, zeroed by k_prep)
    float* mp1   = ws + 4753152;       // 24576
    float* mp2   = ws + 4777728;       // 24576
    float* c     = ws + 4802304;       // 24576
    ushort* Xh   = (ushort*)(ws + 4826880);   // 1572864 ushorts
    ushort* Xl   = (ushort*)(ws + 5613312);
    ushort* Eh   = (ushort*)(ws + 6399744);   // 589824 ushorts
    ushort* El   = (ushort*)(ws + 6694656);

    k_prep<<<1083, 256, 0, stream>>>(nw, xs, ew, Wn, WnT, r1inv, mp0, Xh, Xl, Eh, El);
    k_embed<<<dim3(32, 12), 256, 0, stream>>>(Xh, Xl, Eh, El, eb, inp);
    k_nnmf<<<384, 256, 0, stream>>>(inp, Wn, WnT, r1inv, h, hri, mp0);
    k_alpha_step<<<384, 256, 0, stream>>>(h, hri, Wn, mp0, mp1, c, M, 1);
    k_alpha_step<<<384, 256, 0, stream>>>(h, hri, Wn, mp1, mp2, c, M, 2);
    k_alpha_step<<<384, 256, 0, stream>>>(h, hri, Wn, mp2, mp1, c, M, 3);
    k_projbcast<<<384, 256, 0, stream>>>(M, ow, ob, out);
}

// Round 10
// 137.870 us; speedup vs baseline: 1.2953x; 1.2953x over previous
//
#include <hip/hip_runtime.h>

// Problem constants
#define B_  2
#define S_  1024
#define FIN 768
#define E_  768
#define H_  12
#define DH  64   // = FH = 64

typedef unsigned int uint;
typedef unsigned short ushort;
typedef __attribute__((ext_vector_type(8))) short short8;    // 8 bf16 (4 VGPRs)
typedef __attribute__((ext_vector_type(4))) float floatx4;   // MFMA acc

__device__ __forceinline__ ushort f2bf(float f) {   // RNE float->bf16 bits
    uint u = __float_as_uint(f);
    return (ushort)((u + 0x7fffu + ((u >> 16) & 1u)) >> 16);
}

__device__ __forceinline__ uint4 pack8(const ushort* p) {
    uint4 r;
    r.x = (uint)p[0] | ((uint)p[1] << 16);
    r.y = (uint)p[2] | ((uint)p[3] << 16);
    r.z = (uint)p[4] | ((uint)p[5] << 16);
    r.w = (uint)p[6] | ((uint)p[7] << 16);
    return r;
}

__device__ __forceinline__ void split8v(float4 a, float4 b, short8& hi, short8& lo) {
    float v[8] = {a.x, a.y, a.z, a.w, b.x, b.y, b.z, b.w};
    ushort h[8], l[8];
#pragma unroll
    for (int j = 0; j < 8; ++j) {
        h[j] = f2bf(v[j]);
        l[j] = f2bf(v[j] - __uint_as_float(((uint)h[j]) << 16));
    }
    uint4 H = pack8(h), L = pack8(l);
    hi = *(short8*)&H;
    lo = *(short8*)&L;
}

// ---------------------------------------------------------------------------
// K2+K1 fused: blocks 0..767: MFMA embed (32 tok x 64 out = 1 head; head is
// the FASTEST block dim for L2 x-reuse). Blocks 768..794: W-prep + zeroing.
// Embed: split-bf16 (hi+lo) in-kernel conversion, 3 MFMA/tile-pair.
// 4 waves: wave = 16tok x 32out (1x2 frags of 16x16x32). 27.9 KB LDS.
// ---------------------------------------------------------------------------
__global__ __launch_bounds__(256) void k_embed_prep(const float* __restrict__ xs,
                                                    const float* __restrict__ ew,
                                                    const float* __restrict__ eb,
                                                    const float* __restrict__ nw,
                                                    float* __restrict__ Wn,
                                                    float* __restrict__ WnT,
                                                    float* __restrict__ r1inv,
                                                    float* __restrict__ zbase,
                                                    float* __restrict__ inp) {
    __shared__ __align__(16) unsigned char smem[28160];
    const int tid = threadIdx.x;
    const int bid = blockIdx.x;

    if (bid >= 768) {   // ---- prep blocks ----
        const int pb = bid - 768;
        if (pb == 0) {
            float* Wl = (float*)smem;   // [64][65]
            const int f = tid >> 2, q = tid & 3;
            float v[16];
            float s = 0.f;
#pragma unroll
            for (int i = 0; i < 16; ++i) { v[i] = nw[f * 64 + q * 16 + i]; s += v[i]; }
            s += __shfl_xor(s, 1, 64);
            s += __shfl_xor(s, 2, 64);
            const float inv = 1.f / fmaxf(s, 1e-20f);
#pragma unroll
            for (int i = 0; i < 16; ++i) {
                float w = v[i] * inv;
                Wn[f * 64 + q * 16 + i] = w;
                WnT[(q * 16 + i) * 64 + f] = w;
                Wl[f * 65 + q * 16 + i] = w;
            }
            __syncthreads();
            if (tid < 64) {
                float cs = 0.f;
                for (int ff = 0; ff < 64; ++ff) cs += Wl[ff * 65 + tid];
                float t = fmaxf(cs * (1.f / 64.f), 1e-6f);
                float S = t;
#pragma unroll
                for (int m = 1; m < 64; m <<= 1) S += __shfl_xor(S, m, 64);
                S = fmaxf(S, 1e-20f);
                r1inv[tid] = S / t;   // 1/rec1
            }
        } else {
            const int i = (pb - 1) * 1024 + tid * 4;
            if (i < 26112) {
                float4 z = make_float4(0.f, 0.f, 0.f, 0.f);
                *(float4*)(zbase + i) = z;
            }
        }
        return;
    }

    // ---- embed blocks ----
    const int head = bid % 12;           // fastest -> consecutive blocks share x-tile
    const int tok0 = (bid / 12) * 32;
    ushort* As_hi = (ushort*)smem;               // [32][72]
    ushort* As_lo = As_hi + 32 * 72;
    ushort* Bs_hi = As_lo + 32 * 72;             // [64][72]
    ushort* Bs_lo = Bs_hi + 64 * 72;
    float*  RS    = (float*)(Bs_lo + 64 * 72);   // [2][32]

    const int wv = tid >> 6, lane = tid & 63;
    const int mbase = (wv >> 1) * 16;    // 16-token frag row
    const int nbase = (wv & 1) * 32;     // 32-out half
    const int lm = lane & 15, lq = lane >> 4;

    floatx4 acc[2];
    acc[0] = (floatx4)0.f;
    acc[1] = (floatx4)0.f;

    // staging assignment
    const int arow = tid >> 3, akc = (tid & 7) * 8;    // A: 32 rows x 8 k
    const int brow = tid >> 2, bkq = (tid & 3) * 16;   // B: 64 rows x 16 k
    const float* xrow = xs + (size_t)(tok0 + arow) * FIN + akc;
    const float* wrg  = ew + (size_t)(head * 64 + brow) * FIN + bkq;

    float4 pa[2], pb[4];
#pragma unroll
    for (int c = 0; c < 2; ++c) pa[c] = *(const float4*)(xrow + c * 4);
#pragma unroll
    for (int c = 0; c < 4; ++c) pb[c] = *(const float4*)(wrg + c * 4);

    for (int kb = 0; kb < FIN; kb += 64) {
        __syncthreads();   // previous panel's frag reads done
        {
            ushort ah[8], al[8], bh[16], bl[16];
            float va[8] = {pa[0].x, pa[0].y, pa[0].z, pa[0].w,
                           pa[1].x, pa[1].y, pa[1].z, pa[1].w};
#pragma unroll
            for (int j = 0; j < 8; ++j) {
                ah[j] = f2bf(va[j]);
                al[j] = f2bf(va[j] - __uint_as_float(((uint)ah[j]) << 16));
            }
#pragma unroll
            for (int c4 = 0; c4 < 4; ++c4) {
                float vb[4] = {pb[c4].x, pb[c4].y, pb[c4].z, pb[c4].w};
#pragma unroll
                for (int j = 0; j < 4; ++j) {
                    ushort g = f2bf(vb[j]);
                    bh[c4 * 4 + j] = g;
                    bl[c4 * 4 + j] = f2bf(vb[j] - __uint_as_float(((uint)g) << 16));
                }
            }
            const int aoff = arow * 72 + akc;
            *(uint4*)&As_hi[aoff] = pack8(ah);
            *(uint4*)&As_lo[aoff] = pack8(al);
            const int boff = brow * 72 + bkq;
            *(uint4*)&Bs_hi[boff]     = pack8(bh);
            *(uint4*)&Bs_hi[boff + 8] = pack8(bh + 8);
            *(uint4*)&Bs_lo[boff]     = pack8(bl);
            *(uint4*)&Bs_lo[boff + 8] = pack8(bl + 8);
        }
        __syncthreads();
        if (kb + 64 < FIN) {   // prefetch next panel during compute
#pragma unroll
            for (int c = 0; c < 2; ++c) pa[c] = *(const float4*)(xrow + kb + 64 + c * 4);
#pragma unroll
            for (int c = 0; c < 4; ++c) pb[c] = *(const float4*)(wrg + kb + 64 + c * 4);
        }
#pragma unroll
        for (int ch = 0; ch < 2; ++ch) {
            const int ko = ch * 32 + lq * 8;
            short8 ah = *(const short8*)&As_hi[(mbase + lm) * 72 + ko];
            short8 al = *(const short8*)&As_lo[(mbase + lm) * 72 + ko];
#pragma unroll
            for (int ti = 0; ti < 2; ++ti) {
                short8 bh = *(const short8*)&Bs_hi[(nbase + ti * 16 + lm) * 72 + ko];
                short8 bl = *(const short8*)&Bs_lo[(nbase + ti * 16 + lm) * 72 + ko];
                acc[ti] = __builtin_amdgcn_mfma_f32_16x16x32_bf16(ah, bh, acc[ti], 0, 0, 0);
                acc[ti] = __builtin_amdgcn_mfma_f32_16x16x32_bf16(al, bh, acc[ti], 0, 0, 0);
                acc[ti] = __builtin_amdgcn_mfma_f32_16x16x32_bf16(ah, bl, acc[ti], 0, 0, 0);
            }
        }
    }

    // epilogue: bias, clamp, per-token l1norm over 64 outs, store.
    // C/D: col = lane&15 (out within frag), row = lq*4 + r (token within frag).
    const float b0 = eb[head * 64 + nbase + lm];
    const float b1 = eb[head * 64 + nbase + 16 + lm];
    float xe[2][4];
    float rs[4];
#pragma unroll
    for (int r = 0; r < 4; ++r) {
        float e0 = fmaxf(acc[0][r] + b0, 1e-6f);
        float e1 = fmaxf(acc[1][r] + b1, 1e-6f);
        xe[0][r] = e0; xe[1][r] = e1;
        float p = e0 + e1;
        p += __shfl_xor(p, 1, 64);
        p += __shfl_xor(p, 2, 64);
        p += __shfl_xor(p, 4, 64);
        p += __shfl_xor(p, 8, 64);
        rs[r] = p;
    }
    if (lm == 0) {
#pragma unroll
        for (int r = 0; r < 4; ++r)
            RS[(wv & 1) * 32 + mbase + lq * 4 + r] = rs[r];
    }
    __syncthreads();
    const size_t obase = ((size_t)((tok0 >> 10) * 12 + head) * 1024 + (tok0 & 1023));
#pragma unroll
    for (int r = 0; r < 4; ++r) {
        const int m = mbase + lq * 4 + r;
        const float inv = 1.f / fmaxf(RS[m] + RS[32 + m], 1e-20f);
        float* op = inp + (obase + m) * 64;
        op[nbase + lm]      = xe[0][r] * inv;
        op[nbase + 16 + lm] = xe[1][r] * inv;
    }
}

// ---------------------------------------------------------------------------
// K3 (MFMA, passed R8): NNMF updates, 16 tokens per wave, 384 blocks x 4 waves.
// ---------------------------------------------------------------------------
__device__ __forceinline__ void mfma_matvec(const float srcC[4][4], float* T,
                                            int lm, int lq,
                                            const short8 Bh[4][2],
                                            const short8 Bl[4][2],
                                            floatx4 out[4]) {
#pragma unroll
    for (int nt = 0; nt < 4; ++nt)
#pragma unroll
        for (int r = 0; r < 4; ++r)
            T[(lq * 4 + r) * 68 + nt * 16 + lm] = srcC[nt][r];
    __syncthreads();
    float4 a00 = *(const float4*)&T[lm * 68 + lq * 8];
    float4 a01 = *(const float4*)&T[lm * 68 + lq * 8 + 4];
    float4 a10 = *(const float4*)&T[lm * 68 + 32 + lq * 8];
    float4 a11 = *(const float4*)&T[lm * 68 + 32 + lq * 8 + 4];
    short8 A0h, A0l, A1h, A1l;
    split8v(a00, a01, A0h, A0l);
    split8v(a10, a11, A1h, A1l);
#pragma unroll
    for (int nt = 0; nt < 4; ++nt) {
        floatx4 acc = (floatx4)0.f;
        acc = __builtin_amdgcn_mfma_f32_16x16x32_bf16(A0h, Bh[nt][0], acc, 0, 0, 0);
        acc = __builtin_amdgcn_mfma_f32_16x16x32_bf16(A0l, Bh[nt][0], acc, 0, 0, 0);
        acc = __builtin_amdgcn_mfma_f32_16x16x32_bf16(A0h, Bl[nt][0], acc, 0, 0, 0);
        acc = __builtin_amdgcn_mfma_f32_16x16x32_bf16(A1h, Bh[nt][1], acc, 0, 0, 0);
        acc = __builtin_amdgcn_mfma_f32_16x16x32_bf16(A1l, Bh[nt][1], acc, 0, 0, 0);
        acc = __builtin_amdgcn_mfma_f32_16x16x32_bf16(A1h, Bl[nt][1], acc, 0, 0, 0);
        out[nt] = acc;
    }
}

__global__ __launch_bounds__(256) void k_nnmf(const float* __restrict__ inp,
                                              const float* __restrict__ Wn,
                                              const float* __restrict__ WnT,
                                              const float* __restrict__ r1inv,
                                              float* __restrict__ hout,
                                              float* __restrict__ hriout,
                                              float* __restrict__ mp0) {
    __shared__ float Tb[4][16 * 68];
    const int tid = threadIdx.x, wv = tid >> 6, lane = tid & 63;
    const int lm = lane & 15, lq = lane >> 4;
    float* T = Tb[wv];
    const int rowbase = blockIdx.x * 64 + wv * 16;

    short8 Bt_h[4][2], Bt_l[4][2], Bw_h[4][2], Bw_l[4][2];
#pragma unroll
    for (int nt = 0; nt < 4; ++nt)
#pragma unroll
        for (int kc = 0; kc < 2; ++kc) {
            const int idx = (nt * 16 + lm) * 64 + kc * 32 + lq * 8;
            split8v(*(const float4*)(WnT + idx), *(const float4*)(WnT + idx + 4),
                    Bt_h[nt][kc], Bt_l[nt][kc]);
            split8v(*(const float4*)(Wn + idx), *(const float4*)(Wn + idx + 4),
                    Bw_h[nt][kc], Bw_l[nt][kc]);
        }

    float inpC[4][4];
#pragma unroll
    for (int nt = 0; nt < 4; ++nt)
#pragma unroll
        for (int r = 0; r < 4; ++r)
            inpC[nt][r] = inp[(size_t)(rowbase + lq * 4 + r) * 64 + nt * 16 + lm];
    float r1c[4];
#pragma unroll
    for (int nt = 0; nt < 4; ++nt) r1c[nt] = r1inv[nt * 16 + lm];

    float hC[4][4], recC[4][4];
    {   // ---- iteration 1 (rec1 token-independent) ----
        float qC[4][4];
#pragma unroll
        for (int nt = 0; nt < 4; ++nt)
#pragma unroll
            for (int r = 0; r < 4; ++r) qC[nt][r] = inpC[nt][r] * r1c[nt];
        floatx4 u[4];
        mfma_matvec(qC, T, lm, lq, Bw_h, Bw_l, u);
#pragma unroll
        for (int nt = 0; nt < 4; ++nt)
#pragma unroll
            for (int r = 0; r < 4; ++r)
                hC[nt][r] = fmaxf(u[nt][r] * (1.f / 64.f), 1e-6f);
#pragma unroll
        for (int r = 0; r < 4; ++r) {
            float s = (hC[0][r] + hC[1][r]) + (hC[2][r] + hC[3][r]);
            s += __shfl_xor(s, 1, 64); s += __shfl_xor(s, 2, 64);
            s += __shfl_xor(s, 4, 64); s += __shfl_xor(s, 8, 64);
            const float inv = __builtin_amdgcn_rcpf(fmaxf(s, 1e-20f));
#pragma unroll
            for (int nt = 0; nt < 4; ++nt) hC[nt][r] *= inv;
        }
    }
#pragma unroll 1
    for (int it = 0; it < 2; ++it) {   // ---- iterations 2,3 (full) ----
        floatx4 t[4];
        mfma_matvec(hC, T, lm, lq, Bt_h, Bt_l, t);
        float tC[4][4], qC[4][4];
#pragma unroll
        for (int nt = 0; nt < 4; ++nt)
#pragma unroll
            for (int r = 0; r < 4; ++r) tC[nt][r] = fmaxf(t[nt][r], 1e-6f);
#pragma unroll
        for (int r = 0; r < 4; ++r) {
            float s = (tC[0][r] + tC[1][r]) + (tC[2][r] + tC[3][r]);
            s += __shfl_xor(s, 1, 64); s += __shfl_xor(s, 2, 64);
            s += __shfl_xor(s, 4, 64); s += __shfl_xor(s, 8, 64);
            s = fmaxf(s, 1e-20f);
            const float invS = __builtin_amdgcn_rcpf(s);
#pragma unroll
            for (int nt = 0; nt < 4; ++nt) {
                recC[nt][r] = tC[nt][r] * invS;
                qC[nt][r] = inpC[nt][r] * s * __builtin_amdgcn_rcpf(tC[nt][r]);
            }
        }
        floatx4 u[4];
        mfma_matvec(qC, T, lm, lq, Bw_h, Bw_l, u);
#pragma unroll
        for (int nt = 0; nt < 4; ++nt)
#pragma unroll
            for (int r = 0; r < 4; ++r)
                hC[nt][r] = fmaxf(hC[nt][r] * u[nt][r], 1e-6f);
#pragma unroll
        for (int r = 0; r < 4; ++r) {
            float s = (hC[0][r] + hC[1][r]) + (hC[2][r] + hC[3][r]);
            s += __shfl_xor(s, 1, 64); s += __shfl_xor(s, 2, 64);
            s += __shfl_xor(s, 4, 64); s += __shfl_xor(s, 8, 64);
            const float inv = __builtin_amdgcn_rcpf(fmaxf(s, 1e-20f));
#pragma unroll
            for (int nt = 0; nt < 4; ++nt) hC[nt][r] *= inv;
        }
    }
#pragma unroll
    for (int r = 0; r < 4; ++r) {
        float s = (hC[0][r] + hC[1][r]) + (hC[2][r] + hC[3][r]);
        s += __shfl_xor(s, 1, 64); s += __shfl_xor(s, 2, 64);
        s += __shfl_xor(s, 4, 64); s += __shfl_xor(s, 8, 64);
        const float inv = __builtin_amdgcn_rcpf(fmaxf(s, 1e-20f));
#pragma unroll
        for (int nt = 0; nt < 4; ++nt) hC[nt][r] *= inv;
    }
#pragma unroll
    for (int nt = 0; nt < 4; ++nt)
#pragma unroll
        for (int r = 0; r < 4; ++r) {
            const size_t o = (size_t)(rowbase + lq * 4 + r) * 64 + nt * 16 + lm;
            hout[o] = hC[nt][r];
            hriout[o] = recC[nt][r] * inpC[nt][r];
        }
    float hs[4];
#pragma unroll
    for (int nt = 0; nt < 4; ++nt) {
        float s = (hC[nt][0] + hC[nt][1]) + (hC[nt][2] + hC[nt][3]);
        s += __shfl_xor(s, 16, 64);
        s += __shfl_xor(s, 32, 64);
        hs[nt] = s;
    }
    float mvv = lq == 0 ? hs[0] : lq == 1 ? hs[1] : lq == 2 ? hs[2] : hs[3];
    atomicAdd(&mp0[(size_t)blockIdx.x * 64 + lq * 16 + lm], mvv);
}

// ---------------------------------------------------------------------------
// K4: one alpha iteration per launch, 384 blocks = (bh) x (64-o chunk).
// ---------------------------------------------------------------------------
__global__ __launch_bounds__(256) void k_alpha_step(const float* __restrict__ hin,
                                                    const float* __restrict__ hri,
                                                    const float* __restrict__ Wn,
                                                    const float* __restrict__ mp_in,
                                                    float* __restrict__ mp_out,
                                                    float* __restrict__ c,
                                                    float* __restrict__ M,
                                                    int it) {
    __shared__ float mred[4][64];
    __shared__ float mv[64];
    __shared__ float vv[64];
    __shared__ float cl[64];
    const int tid = threadIdx.x;
    const int bh = blockIdx.x >> 4;
    const int chunk = blockIdx.x & 15;
    const size_t rowbase = (size_t)bh * 1024 + chunk * 64;

    {
        int f = tid & 63, p = tid >> 6;
        float s = 0.f;
#pragma unroll
        for (int pp = 0; pp < 4; ++pp)
            s += mp_in[((size_t)bh * 16 + p * 4 + pp) * 64 + f];
        mred[p][f] = s;
    }
    __syncthreads();
    if (tid < 64)
        mv[tid] = (mred[0][tid] + mred[1][tid]) + (mred[2][tid] + mred[3][tid]);
    __syncthreads();
    {
        int d = tid & 63, qq = tid >> 6;
        float r = 0.f;
#pragma unroll
        for (int ff = 0; ff < 16; ++ff)
            r = fmaf(mv[qq * 16 + ff], Wn[(size_t)(qq * 16 + ff) * 64 + d], r);
        mred[qq][d] = r;
    }
    __syncthreads();
    if (tid < 64)
        vv[tid] = 1.f / (((mred[0][tid] + mred[1][tid]) + (mred[2][tid] + mred[3][tid])) + 1e-20f);
    __syncthreads();
    {
        int o = tid >> 2, dq = tid & 3;
        const float* rp = hri + (rowbase + o) * 64 + dq * 16;
        float dot = 0.f;
#pragma unroll
        for (int t4 = 0; t4 < 16; t4 += 4) {
            float4 r4 = *(const float4*)(rp + t4);
            dot = fmaf(r4.x, vv[dq * 16 + t4 + 0], dot);
            dot = fmaf(r4.y, vv[dq * 16 + t4 + 1], dot);
            dot = fmaf(r4.z, vv[dq * 16 + t4 + 2], dot);
            dot = fmaf(r4.w, vv[dq * 16 + t4 + 3], dot);
        }
        dot += __shfl_xor(dot, 1, 64);
        dot += __shfl_xor(dot, 2, 64);
        float cn = dot;
        if (it >= 2) cn *= c[rowbase + o];
        if (dq == 0) { c[rowbase + o] = cn; cl[o] = cn; }
    }
    __syncthreads();
    {
        const int f4 = (tid & 15) * 4, ogr = tid >> 4;
        float4 a = make_float4(0.f, 0.f, 0.f, 0.f);
#pragma unroll
        for (int oi = 0; oi < 4; ++oi) {
            int o = ogr * 4 + oi;
            float4 h4 = *(const float4*)(hin + (rowbase + o) * 64 + f4);
            float cv = cl[o];
            a.x = fmaf(h4.x, cv, a.x); a.y = fmaf(h4.y, cv, a.y);
            a.z = fmaf(h4.z, cv, a.z); a.w = fmaf(h4.w, cv, a.w);
        }
        a.x += __shfl_xor(a.x, 16, 64); a.y += __shfl_xor(a.y, 16, 64);
        a.z += __shfl_xor(a.z, 16, 64); a.w += __shfl_xor(a.w, 16, 64);
        a.x += __shfl_xor(a.x, 32, 64); a.y += __shfl_xor(a.y, 32, 64);
        a.z += __shfl_xor(a.z, 32, 64); a.w += __shfl_xor(a.w, 32, 64);
        const int w = tid >> 6;
        if ((tid & 63) < 16) *(float4*)&mred[w][(tid & 15) * 4] = a;
    }
    __syncthreads();
    if (tid < 64) {
        float s = (mred[0][tid] + mred[1][tid]) + (mred[2][tid] + mred[3][tid]);
        if (it == 3) atomicAdd(&M[(size_t)bh * 64 + tid], s);
        else mp_out[((size_t)bh * 16 + chunk) * 64 + tid] = s;
    }
}

// ---------------------------------------------------------------------------
// K5: out-projection + broadcast, 384 blocks = (b) x (12 out-seg) x (16 rowgrp).
// ---------------------------------------------------------------------------
__global__ __launch_bounds__(256) void k_projbcast(const float* __restrict__ M,
                                                   const float* __restrict__ ow,
                                                   const float* __restrict__ ob,
                                                   float* __restrict__ out) {
    __shared__ float Ml[768];
    __shared__ float ps[4][64];
    __shared__ float yseg[64];
    const int tid = threadIdx.x;
    const int b = blockIdx.x / 192;
    const int rem = blockIdx.x - b * 192;
    const int jt = rem >> 4, rg = rem & 15;
    for (int i = tid; i < 768; i += 256) Ml[i] = M[b * 768 + i];
    __syncthreads();
    const int jj = tid & 63, part = tid >> 6;
    const int j = jt * 64 + jj;
    const float* row = ow + (size_t)j * 768 + part * 192;
    float acc = 0.f;
    for (int t = 0; t < 192; t += 4) {
        float4 w4 = *(const float4*)(row + t);
        acc = fmaf(w4.x, Ml[part * 192 + t + 0], acc);
        acc = fmaf(w4.y, Ml[part * 192 + t + 1], acc);
        acc = fmaf(w4.z, Ml[part * 192 + t + 2], acc);
        acc = fmaf(w4.w, Ml[part * 192 + t + 3], acc);
    }
    ps[part][jj] = acc;
    __syncthreads();
    if (tid < 64)
        yseg[tid] = ps[0][tid] + ps[1][tid] + ps[2][tid] + ps[3][tid] + ob[jt * 64 + tid];
    __syncthreads();
    const int r0 = tid >> 2, c4 = (tid & 3) * 16;
    float4 v4[4];
#pragma unroll
    for (int q = 0; q < 4; ++q) v4[q] = *(const float4*)&yseg[c4 + q * 4];
    float* dst = out + ((size_t)(b * 1024 + rg * 64 + r0)) * 768 + jt * 64 + c4;
#pragma unroll
    for (int q = 0; q < 4; ++q) *(float4*)(dst + q * 4) = v4[q];
}

extern "C" void kernel_launch(void* const* d_in, const int* in_sizes, int n_in,
                              void* d_out, int out_size, void* d_ws, size_t ws_size,
                              hipStream_t stream) {
    const float* xs = (const float*)d_in[0];  // [2,1024,768]
    const float* ew = (const float*)d_in[1];  // [768,768]
    const float* eb = (const float*)d_in[2];  // [768]
    const float* nw = (const float*)d_in[3];  // [64,64]
    const float* ow = (const float*)d_in[4];  // [768,768]
    const float* ob = (const float*)d_in[5];  // [768]
    float* out = (float*)d_out;               // [2,1024,768]

    float* ws    = (float*)d_ws;
    float* inp   = ws;                 // 1572864
    float* h     = ws + 1572864;       // 1572864
    float* hri   = ws + 3145728;       // 1572864
    float* Wn    = ws + 4718592;       // 4096
    float* WnT   = ws + 4722688;       // 4096
    float* r1inv = ws + 4726784;       // 256
    float* mp0   = ws + 4727040;       // 24576 (atomic target, zeroed in-kernel)
    float* M     = ws + 4751616;       // 1536  (atomic target, zeroed in-kernel)
    float* mp1   = ws + 4753152;       // 24576
    float* mp2   = ws + 4777728;       // 24576
    float* c     = ws + 4802304;       // 24576

    k_embed_prep<<<795, 256, 0, stream>>>(xs, ew, eb, nw, Wn, WnT, r1inv, mp0, inp);
    k_nnmf<<<384, 256, 0, stream>>>(inp, Wn, WnT, r1inv, h, hri, mp0);
    k_alpha_step<<<384, 256, 0, stream>>>(h, hri, Wn, mp0, mp1, c, M, 1);
    k_alpha_step<<<384, 256, 0, stream>>>(h, hri, Wn, mp1, mp2, c, M, 2);
    k_alpha_step<<<384, 256, 0, stream>>>(h, hri, Wn, mp2, mp1, c, M, 3);
    k_projbcast<<<384, 256, 0, stream>>>(M, ow, ob, out);
}